// Round 5
// baseline (176.835 us; speedup 1.0000x reference)
//
#include <hip/hip_runtime.h>

// CostTokenizer R11: buy LDS ILP with registers (win[7] batch).
//   Post-mortem R9/R10: prefetch abandoned (spill at bounds(256,5); clean but
//   -26% at bounds(256,4) — compiler squeezed schedule to keep pv live).
//   R8 Little's-law: 2.5 blocks/CU resident, block latency ~34 us vs ~4 us
//   pipe content -> waves ~90% stalled INSIDE phase 1: 49 dependent
//   ds_read_b128->fmaf pairs with only ~2 reads in flight at VGPR=64
//   (compiler sat on the 64-reg occupancy boundary) -> ~60 cy exposed
//   latency per read.
//   Fix: batch each b-column's 7 reads into statically-indexed win[7]
//   BEFORE the FMAs -> 7 ds_read_b128 in flight, staged lgkmcnt waits
//   (m97 pattern), exposed latency /7. Costs ~28 VGPR -> ~100 total:
//   5 waves/SIMD, still >= the 4-wave bound; grid (5.25/CU) is the cap.
//   Spill gate: WRITE_SIZE must stay exactly 64,512 KB.
//  - RULE (R9): with 256-thread blocks and >=49 floats/lane live, never
//    request >4 waves/EU in launch_bounds (HW quantum forces sub-64 alloc).
//  - R6 rule kept: every loop indexing a register array is fully unrolled;
//    `unroll 1` only on loops touching LDS/global alone (scratch-spill trap).
//  - bank accounting: phase-1 b128 reads deliver 8 dwords/bank/instr =
//    perfectly balanced 8-cy issue; the 5.6M conflict count is ~free 2-way
//    staging aliasing (m136).
//  - LDS union (reduce slices alias dead halos, 25.1 KB) + XCD column swizzle.
//
//  corr[k] = sum_c f1[c,h,w] * f2[c, (h-dy)%H, (w-dx)%W], k = (dy+3)*7 + (dx+3)
//  tok[t,b,d,h,w] = b[d] + (1/sqrt(C)) * sum_k corr[k] * w[k,d]

#define TD 192
#define HSTRIDE 26   // halo row stride in float4

template<int C, int H, int W, int TX, int TY>
__device__ __forceinline__ void level_tile(
    const float* __restrict__ lvl, const float* __restrict__ wm,
    const float* __restrict__ bias, float* __restrict__ out,
    int r, float scale, float* __restrict__ smem)
{
    const int HW = H * W;
    // XCD column-affinity: tiles of one column (pair,tX) are == mod 8 in bid
    const int xcd = r & 7, q = r >> 3;
    const int tY  = q % TY;
    const int col = (q / TY) * 8 + xcd;      // [0, 4*TX)
    const int pair = col / TX, tX = col % TX;

    const int t  = pair >> 1, bb = pair & 1;
    const float* f1 = lvl + (t * 2 + bb) * C * HW;
    const float* f2 = lvl + ((t + 1) * 2 + bb) * C * HW;

    const int tid  = threadIdx.x;
    const int lane = tid & 63;
    const int g    = tid >> 6;               // wave: channel group / d group
    const int tx   = lane & 15, ty = lane >> 4;   // lane owns row y0+ty
    const int x0   = tX * 16, y0 = tY * 4;
    const int x    = x0 + tx;
    const int y    = y0 + ty;

    float4* h = (float4*)smem + g * (10 * HSTRIDE);  // wave halo: 10 rows

    // staging offsets for halo cells p in [0,220): row=p/22, col=p%22
    int goff[4], loff[4];
#pragma unroll
    for (int i = 0; i < 4; ++i) {
        int p = lane + i * 64;
        int rr = p / 22, cc = p - rr * 22;
        int gy = y0 - 3 + rr; if (gy < 0) gy += H; if (gy >= H) gy -= H;
        int gx = x0 - 3 + cc; if (gx < 0) gx += W; if (gx >= W) gx -= W;
        goff[i] = gy * W + gx;
        loff[i] = rr * HSTRIDE + cc;
    }

    float acc[49];
#pragma unroll
    for (int k = 0; k < 49; ++k) acc[k] = 0.f;

    // ---- phase 1: correlation, wave-synchronous (wave-private halo) ----
    const int NCH = C / 16;                  // 4-channel chunks per wave
    const float* f2c = f2 + g * (C / 4) * HW;
    const float* f1c = f1 + g * (C / 4) * HW + y * W + x;
#pragma unroll 1
    for (int cg = 0; cg < NCH; ++cg) {       // body touches LDS/global only via
#pragma unroll                               // fully-unrolled inner loops
        for (int i = 0; i < 4; ++i) {
            if (i < 3 || lane < 28) {        // 220 cells
                const float* s = f2c + goff[i];
                float4 v; v.x = s[0]; v.y = s[HW]; v.z = s[2 * HW]; v.w = s[3 * HW];
                h[loff[i]] = v;
            }
        }
        float a0 = f1c[0], a1 = f1c[HW], a2 = f1c[2 * HW], a3 = f1c[3 * HW];
        f2c += 4 * HW; f1c += 4 * HW;
        // same-wave LDS RAW: compiler lgkmcnt waits cover it
#pragma unroll
        for (int b = 0; b < 7; ++b) {        // FULL unroll: indexes acc/win
            const float4* hp = h + ty * HSTRIDE + (tx + 6 - b);
            float4 win[7];                   // 7 ds_read_b128 in flight
#pragma unroll
            for (int a = 0; a < 7; ++a)
                win[a] = hp[(6 - a) * HSTRIDE];
#pragma unroll
            for (int a = 0; a < 7; ++a) {
                float s0 = acc[a * 7 + b];
                s0 = fmaf(a0, win[a].x, s0); s0 = fmaf(a1, win[a].y, s0);
                s0 = fmaf(a2, win[a].z, s0); s0 = fmaf(a3, win[a].w, s0);
                acc[a * 7 + b] = s0;
            }
        }
    }

    // ---- phase 2: cross-wave reduce; slices alias dead halo space ----
    __syncthreads();                         // all waves done with halos
    float* s0p = smem;                       // [49][64]
    float* s1p = smem + 49 * 64;
    if (g >= 2) {
        float* dst = (g == 2) ? s0p : s1p;
#pragma unroll
        for (int k = 0; k < 49; ++k)         // FULL unroll: indexes acc
            dst[k * 64 + lane] = acc[k];
    }
    __syncthreads();
    if (g < 2) {
        float* dst = (g == 0) ? s0p : s1p;
#pragma unroll
        for (int k = 0; k < 49; ++k)         // FULL unroll: indexes acc
            dst[k * 64 + lane] += acc[k];
    }
    __syncthreads();

    // ---- phase 3: 49 -> 192, wave g owns d in [48g, 48g+48), 1 px/lane ----
    const int dbase = __builtin_amdgcn_readfirstlane(g * 48);
    float sA[48];
#pragma unroll
    for (int j = 0; j < 48; ++j) sA[j] = bias[dbase + j];
#pragma unroll 2
    for (int k = 0; k < 49; ++k) {           // unroll 2: two w-rows in flight
        float c0 = (s0p[k * 64 + lane] + s1p[k * 64 + lane]) * scale;
        const float* wr = wm + k * TD + dbase;   // wave-uniform -> s_load
#pragma unroll
        for (int j = 0; j < 48; ++j)         // FULL unroll: indexes sA
            sA[j] = fmaf(wr[j], c0, sA[j]);
    }
    float* op = out + (pair * TD + dbase) * HW + y * W + x;
#pragma unroll
    for (int j = 0; j < 48; ++j)             // FULL unroll: indexes sA
        op[j * HW] = sA[j];
}

__global__ __launch_bounds__(256, 4)
void cost_tokenizer(const float* __restrict__ l1, const float* __restrict__ l2,
                    const float* __restrict__ l3,
                    const float* __restrict__ w1, const float* __restrict__ b1,
                    const float* __restrict__ w2, const float* __restrict__ b2,
                    const float* __restrict__ w3, const float* __restrict__ b3,
                    float* __restrict__ out)
{
    __shared__ __align__(16) float smem[6272];  // max(2*49*64, 4*10*26*4) f = 25.1 KB
    int bid = blockIdx.x;
    // heavy levels first: L3 (12 chunks/wave), L2 (8), L1 (4)
    if (bid < 64) {
        level_tile<192, 32, 32, 2, 8>(l3, w3, b3, out + 15728640,
                                      bid, 0.072168783648703216f, smem);
    } else if (bid < 320) {
        level_tile<128, 64, 64, 4, 16>(l2, w2, b2, out + 12582912,
                                       bid - 64, 0.088388347648318447f, smem);
    } else {
        level_tile<64, 128, 128, 8, 32>(l1, w1, b1, out,
                                        bid - 320, 0.125f, smem);
    }
}

extern "C" void kernel_launch(void* const* d_in, const int* in_sizes, int n_in,
                              void* d_out, int out_size, void* d_ws, size_t ws_size,
                              hipStream_t stream)
{
    const float* l1 = (const float*)d_in[0];
    const float* l2 = (const float*)d_in[1];
    const float* l3 = (const float*)d_in[2];
    const float* w1 = (const float*)d_in[3];
    const float* b1 = (const float*)d_in[4];
    const float* w2 = (const float*)d_in[5];
    const float* b2 = (const float*)d_in[6];
    const float* w3 = (const float*)d_in[7];
    const float* b3 = (const float*)d_in[8];
    float* out = (float*)d_out;

    hipLaunchKernelGGL(cost_tokenizer, dim3(1344), dim3(256), 0, stream,
                       l1, l2, l3, w1, b1, w2, b2, w3, b3, out);
}